// Round 1
// baseline (271.757 us; speedup 1.0000x reference)
//
#include <hip/hip_runtime.h>

#define NC 19
#define NB 10
#define NCELL (NC * NB)            // 190
#define NPART (3 * NCELL + 2 * NC) // 608: conf[190] pred[190] acc[190] psum[19] inval[19]
#define REP 4

// ---------------------------------------------------------------------------
// Pass 1: per-pixel softmax + binned accumulation.
// LDS histogram with REP replicas (lane&3) to avoid same-address serialization.
// Bin-0 (87% of entries) is NOT atomically accumulated: recovered later via
//   pred(c,0) = valid(c) - sum_{b>=1} pred(c,b)
//   conf(c,0) = psum(c)  - sum_{b>=1} conf(c,b)
// psum kept in per-thread registers (static unroll -> stays in VGPRs).
// ---------------------------------------------------------------------------
__global__ __launch_bounds__(256, 3) void cce_pass1(
    const float* __restrict__ logits, const int* __restrict__ tgt,
    float* __restrict__ gacc, int hw)
{
    constexpr int O_CONF = 0;
    constexpr int O_PRED = REP * NCELL;               // 760
    constexpr int O_ACC  = 2 * REP * NCELL;           // 1520
    constexpr int O_PSUM = 3 * REP * NCELL;           // 2280
    constexpr int O_INV  = 3 * REP * NCELL + REP * NC;// 2356
    constexpr int LDS_N  = O_INV + NC;                // 2375 floats = 9.5 KB

    __shared__ float lds[LDS_N];
    for (int i = threadIdx.x; i < LDS_N; i += blockDim.x) lds[i] = 0.0f;
    __syncthreads();

    const int rep = threadIdx.x & (REP - 1);
    float psum[NC];
#pragma unroll
    for (int c = 0; c < NC; ++c) psum[c] = 0.0f;

    const int ngroups  = hw >> 2;
    const int tid      = blockIdx.x * blockDim.x + threadIdx.x;
    const int nthreads = gridDim.x * blockDim.x;

    for (int g = tid; g < ngroups; g += nthreads) {
        float x[NC][4];
#pragma unroll
        for (int c = 0; c < NC; ++c) {
            float4 v = *reinterpret_cast<const float4*>(logits + (size_t)c * hw + 4 * (size_t)g);
            x[c][0] = v.x; x[c][1] = v.y; x[c][2] = v.z; x[c][3] = v.w;
        }
        const int4 t4 = *reinterpret_cast<const int4*>(tgt + 4 * (size_t)g);
        const int tt[4] = {t4.x, t4.y, t4.z, t4.w};

#pragma unroll
        for (int k = 0; k < 4; ++k) {
            float m = x[0][k];
#pragma unroll
            for (int c = 1; c < NC; ++c) m = fmaxf(m, x[c][k]);
            float e[NC];
            float s = 0.0f;
#pragma unroll
            for (int c = 0; c < NC; ++c) { e[c] = expf(x[c][k] - m); s += e[c]; }
            const float rinv = 1.0f / s;
            const int t = tt[k];
            float ptgt = 0.0f;
#pragma unroll
            for (int c = 0; c < NC; ++c) {
                const float p = e[c] * rinv;
                psum[c] += p;
                if (c == t) ptgt = p;                 // cndmask (c is compile-time)
                const float pb = p * 10.0f;
                if (pb > 1.0f) {                      // <=> bin >= 1 (and p>0)
                    int bin = (int)ceilf(pb) - 1;
                    if (bin > NB - 1) bin = NB - 1;
                    atomicAdd(&lds[O_CONF + rep * NCELL + c * NB + bin], p);
                    atomicAdd(&lds[O_PRED + rep * NCELL + c * NB + bin], 1.0f);
                }
                if (!(p > 0.0f)) atomicAdd(&lds[O_INV + c], 1.0f); // rare (underflow)
            }
            if (ptgt > 0.0f) {                        // no_acc: direct, 1 atomic/pixel
                int bt = (int)ceilf(ptgt * 10.0f) - 1;
                if (bt < 0) bt = 0;
                if (bt > NB - 1) bt = NB - 1;
                atomicAdd(&lds[O_ACC + rep * NCELL + t * NB + bt], 1.0f);
            }
        }
    }
#pragma unroll
    for (int c = 0; c < NC; ++c)
        atomicAdd(&lds[O_PSUM + rep * NC + c], psum[c]);
    __syncthreads();

    // Reduce replicas and push block partials to global accumulators.
    for (int j = threadIdx.x; j < NPART; j += blockDim.x) {
        float v = 0.0f;
        if (j < NCELL) {
            for (int r = 0; r < REP; ++r) v += lds[O_CONF + r * NCELL + j];
        } else if (j < 2 * NCELL) {
            for (int r = 0; r < REP; ++r) v += lds[O_PRED + r * NCELL + (j - NCELL)];
        } else if (j < 3 * NCELL) {
            for (int r = 0; r < REP; ++r) v += lds[O_ACC + r * NCELL + (j - 2 * NCELL)];
        } else if (j < 3 * NCELL + NC) {
            for (int r = 0; r < REP; ++r) v += lds[O_PSUM + r * NC + (j - 3 * NCELL)];
        } else {
            v = lds[O_INV + (j - 3 * NCELL - NC)];
        }
        atomicAdd(&gacc[j], v);
    }
}

// ---------------------------------------------------------------------------
// Pass 2: bin-0 corrections + 190-cell loss reduction (double precision).
// gacc layout: [0,190) conf, [190,380) pred, [380,570) acc, [570,589) psum,
//              [589,608) inval.
// ---------------------------------------------------------------------------
__global__ void cce_pass2(const float* __restrict__ gacc, float* __restrict__ out, int hw)
{
    __shared__ double fin[NPART];
    const int j = threadIdx.x; // blockDim = 640
    if (j < NPART) fin[j] = (double)gacc[j];
    __syncthreads();

    if (j < NC) {
        double spred = 0.0, sconf = 0.0;
        for (int b = 1; b < NB; ++b) {
            spred += fin[NCELL + j * NB + b];
            sconf += fin[j * NB + b];
        }
        const double validc = (double)hw - fin[3 * NCELL + NC + j];
        fin[NCELL + j * NB] = validc - spred;          // pred(c,0)
        fin[j * NB]         = fin[3 * NCELL + j] - sconf; // conf(c,0)
    }
    __syncthreads();

    if (j < 64) {
        double tot = 0.0;
        for (int c = j; c < NCELL; c += 64) tot += fin[NCELL + c];
#pragma unroll
        for (int o = 32; o > 0; o >>= 1) tot += __shfl_down(tot, o);
        tot = __shfl(tot, 0);

        double loss = 0.0;
        for (int c = j; c < NCELL; c += 64) {
            const double pred = fin[NCELL + c];
            const double conf = fin[c];
            const double acc  = fin[2 * NCELL + c];
            const double d    = (acc - conf) / (pred + 1e-13);
            loss += d * d * (pred / tot);
        }
#pragma unroll
        for (int o = 32; o > 0; o >>= 1) loss += __shfl_down(loss, o);
        if (j == 0) out[0] = (float)loss;
    }
}

extern "C" void kernel_launch(void* const* d_in, const int* in_sizes, int n_in,
                              void* d_out, int out_size, void* d_ws, size_t ws_size,
                              hipStream_t stream)
{
    const float* logits = (const float*)d_in[0];
    const int*   tgt    = (const int*)d_in[1];
    float*       gacc   = (float*)d_ws;
    const int    hw     = in_sizes[1]; // 1024*2048

    hipMemsetAsync(gacc, 0, NPART * sizeof(float), stream);
    cce_pass1<<<512, 256, 0, stream>>>(logits, tgt, gacc, hw);
    cce_pass2<<<1, 640, 0, stream>>>(gacc, (float*)d_out, hw);
}